// Round 1
// baseline (1150.215 us; speedup 1.0000x reference)
//
#include <hip/hip_runtime.h>
#include <math.h>

#define DIM 32
#define BLK 256
#define TS  128     // j-tile staged in LDS
#define JSPLIT 8    // j-chunks -> grid.y (1024 blocks total)

// out[i] = sum_j exp(-ls*||x_i-y_j||^2) = 2^(a_i) * sum_j 2^(bf_j + mf*dot_ij)
//   c2 = -ls*log2(e)  (fp64);  a_i = c2*||x_i||^2 (fp64, applied exactly in epilogue)
//   bf_j = (float)(c2*||y_j||^2)  (random rounding across j -> harmless)
//   mf = (float)(-2*c2); dot accumulated in fp32 (random per-pair error)
//   per-tile fp32 partial sums flushed to fp64; fp64 atomics into d_ws.

__global__ __launch_bounds__(BLK) void rbf_prep(
    const float* __restrict__ lsp, const float* __restrict__ x,
    const float* __restrict__ y, int n, int m,
    double* __restrict__ acc, double* __restrict__ scale,
    float* __restrict__ bf)
{
    int i = blockIdx.x * BLK + threadIdx.x;
    const double c2 = -(double)lsp[0] * 1.4426950408889634074; // -ls*log2(e)
    if (i < n) {
        const float* xp = x + (size_t)i * DIM;
        double xs = 0.0;
        #pragma unroll
        for (int d = 0; d < DIM; ++d) { double v = (double)xp[d]; xs = fma(v, v, xs); }
        acc[i] = 0.0;
        scale[i] = exp2(c2 * xs);   // fp64, exact per-i correction factor
    }
    if (i < m) {
        const float* yp = y + (size_t)i * DIM;
        double ys = 0.0;
        #pragma unroll
        for (int d = 0; d < DIM; ++d) { double v = (double)yp[d]; ys = fma(v, v, ys); }
        bf[i] = (float)(c2 * ys);
    }
}

__global__ __launch_bounds__(BLK, 4) void rbf_main(
    const float* __restrict__ lsp, const float* __restrict__ x,
    const float* __restrict__ y, const float* __restrict__ bf,
    double* __restrict__ acc, int chunk_j)
{
    __shared__ float ytile[TS * DIM];   // 16 KB
    __shared__ float bftile[TS];

    const int tid = threadIdx.x;
    const int i = blockIdx.x * BLK + tid;      // one output row per thread
    const int jbase = blockIdx.y * chunk_j;

    const double c2 = -(double)lsp[0] * 1.4426950408889634074;
    const float mf = (float)(-2.0 * c2);       // = 2*ls*log2(e)

    // x row pre-scaled by mf (rounding is random across d, harmless)
    float xr[DIM];
    {
        const float4* xp = (const float4*)(x + (size_t)i * DIM);
        #pragma unroll
        for (int q = 0; q < DIM / 4; ++q) {
            float4 v = xp[q];
            xr[4*q+0] = v.x * mf; xr[4*q+1] = v.y * mf;
            xr[4*q+2] = v.z * mf; xr[4*q+3] = v.w * mf;
        }
    }

    double accd = 0.0;
    const int ntiles = chunk_j / TS;
    for (int t = 0; t < ntiles; ++t) {
        const int jt = jbase + t * TS;
        __syncthreads();
        {   // stage y tile: 4096 floats, coalesced float4
            const float4* src = (const float4*)(y + (size_t)jt * DIM);
            float4* dst = (float4*)ytile;
            #pragma unroll
            for (int q = 0; q < (TS * DIM / 4) / BLK; ++q)
                dst[q * BLK + tid] = src[q * BLK + tid];
            if (tid < TS) bftile[tid] = bf[jt + tid];
        }
        __syncthreads();

        float accf = 0.0f;   // fp32 partial over <=128 terms, then fp64 flush
        #pragma unroll 2
        for (int jj = 0; jj < TS; ++jj) {
            const float4* yv = (const float4*)(ytile + jj * DIM); // wave-uniform broadcast
            float f = bftile[jj];
            #pragma unroll
            for (int q = 0; q < DIM / 4; ++q) {
                float4 v = yv[q];
                f = __builtin_fmaf(xr[4*q+0], v.x, f);
                f = __builtin_fmaf(xr[4*q+1], v.y, f);
                f = __builtin_fmaf(xr[4*q+2], v.z, f);
                f = __builtin_fmaf(xr[4*q+3], v.w, f);
            }
            accf += __builtin_amdgcn_exp2f(f);   // v_exp_f32
        }
        accd += (double)accf;
    }
    atomicAdd(&acc[i], accd);   // fp64 atomic, 8 writers per address
}

__global__ __launch_bounds__(BLK) void rbf_finish(
    const double* __restrict__ acc, const double* __restrict__ scale,
    float* __restrict__ out, int n)
{
    int i = blockIdx.x * BLK + threadIdx.x;
    if (i < n) out[i] = (float)(acc[i] * scale[i]);
}

extern "C" void kernel_launch(void* const* d_in, const int* in_sizes, int n_in,
                              void* d_out, int out_size, void* d_ws, size_t ws_size,
                              hipStream_t stream)
{
    const float* ls = (const float*)d_in[0];
    const float* x  = (const float*)d_in[1];
    const float* y  = (const float*)d_in[2];
    const int n = in_sizes[1] / DIM;   // 32768
    const int m = in_sizes[2] / DIM;   // 32768
    float* out = (float*)d_out;

    // ws layout: double acc[n] | double scale[n] | float bf[m]  (640 KB total)
    char* ws = (char*)d_ws;
    double* acc   = (double*)ws;
    double* scale = (double*)(ws + (size_t)n * sizeof(double));
    float*  bf    = (float*)(ws + (size_t)n * 2 * sizeof(double));

    const int nm = (n > m) ? n : m;
    rbf_prep<<<(nm + BLK - 1) / BLK, BLK, 0, stream>>>(ls, x, y, n, m, acc, scale, bf);

    const int chunk = m / JSPLIT;
    dim3 grid(n / BLK, JSPLIT);
    rbf_main<<<grid, BLK, 0, stream>>>(ls, x, y, bf, acc, chunk);

    rbf_finish<<<(n + BLK - 1) / BLK, BLK, 0, stream>>>(acc, scale, out, n);
}

// Round 2
// 870.192 us; speedup vs baseline: 1.3218x; 1.3218x over previous
//
#include <hip/hip_runtime.h>
#include <math.h>

#define DIM 32
#define BLK 256
#define TS  128     // j-tile staged in LDS
#define R   4       // rows (i) per thread
#define JSPLIT 16   // j-chunks -> grid.y  (grid = 32 x 16 = 512 blocks = 2/CU)

// out[i] = sum_j exp(-ls*||x_i-y_j||^2) = 2^(a_i) * sum_j 2^(bf_j + mf*dot_ij)
//   c2 = -ls*log2(e) (fp64); a_i = c2*||x_i||^2 applied exactly in fp64 epilogue
//   bf_j = (float)(c2*||y_j||^2); mf = (float)(-2*c2); dot in fp32 (random err)
//   fp32 partial sums per 128-tile flushed to fp64; fp64 atomics into d_ws.
// R=4 register blocking: y-tile LDS broadcast reads amortized over 4 rows.

__global__ __launch_bounds__(BLK) void rbf_prep(
    const float* __restrict__ lsp, const float* __restrict__ x,
    const float* __restrict__ y, int n, int m,
    double* __restrict__ acc, double* __restrict__ scale,
    float* __restrict__ bf)
{
    int i = blockIdx.x * BLK + threadIdx.x;
    const double c2 = -(double)lsp[0] * 1.4426950408889634074; // -ls*log2(e)
    if (i < n) {
        const float* xp = x + (size_t)i * DIM;
        double xs = 0.0;
        #pragma unroll
        for (int d = 0; d < DIM; ++d) { double v = (double)xp[d]; xs = fma(v, v, xs); }
        acc[i] = 0.0;
        scale[i] = exp2(c2 * xs);   // fp64, exact per-i correction factor
    }
    if (i < m) {
        const float* yp = y + (size_t)i * DIM;
        double ys = 0.0;
        #pragma unroll
        for (int d = 0; d < DIM; ++d) { double v = (double)yp[d]; ys = fma(v, v, ys); }
        bf[i] = (float)(c2 * ys);
    }
}

__global__ __launch_bounds__(BLK, 2) void rbf_main(
    const float* __restrict__ lsp, const float* __restrict__ x,
    const float* __restrict__ y, const float* __restrict__ bf,
    double* __restrict__ acc, int chunk_j)
{
    __shared__ float ytile[TS * DIM];   // 16 KB
    __shared__ float bftile[TS];

    const int tid = threadIdx.x;
    const int i0 = blockIdx.x * (BLK * R) + tid;   // rows i0 + r*BLK
    const int jbase = blockIdx.y * chunk_j;

    const double c2 = -(double)lsp[0] * 1.4426950408889634074;
    const float mf = (float)(-2.0 * c2);           // = 2*ls*log2(e)

    // x rows pre-scaled by mf (rounding random across d, harmless)
    float xr[R][DIM];
    #pragma unroll
    for (int r = 0; r < R; ++r) {
        const float4* xp = (const float4*)(x + (size_t)(i0 + r * BLK) * DIM);
        #pragma unroll
        for (int q = 0; q < DIM / 4; ++q) {
            float4 v = xp[q];
            xr[r][4*q+0] = v.x * mf; xr[r][4*q+1] = v.y * mf;
            xr[r][4*q+2] = v.z * mf; xr[r][4*q+3] = v.w * mf;
        }
    }

    double accd[R];
    #pragma unroll
    for (int r = 0; r < R; ++r) accd[r] = 0.0;

    const int ntiles = chunk_j / TS;
    for (int t = 0; t < ntiles; ++t) {
        const int jt = jbase + t * TS;
        __syncthreads();
        {   // stage y tile: 4096 floats, coalesced float4
            const float4* src = (const float4*)(y + (size_t)jt * DIM);
            float4* dst = (float4*)ytile;
            #pragma unroll
            for (int q = 0; q < (TS * DIM / 4) / BLK; ++q)
                dst[q * BLK + tid] = src[q * BLK + tid];
            if (tid < TS) bftile[tid] = bf[jt + tid];
        }
        __syncthreads();

        float accf[R];
        #pragma unroll
        for (int r = 0; r < R; ++r) accf[r] = 0.0f;

        #pragma unroll 2
        for (int jj = 0; jj < TS; ++jj) {
            float yv[DIM];
            const float4* ys = (const float4*)(ytile + jj * DIM); // broadcast
            #pragma unroll
            for (int q = 0; q < DIM / 4; ++q) {
                float4 v = ys[q];
                yv[4*q+0] = v.x; yv[4*q+1] = v.y;
                yv[4*q+2] = v.z; yv[4*q+3] = v.w;
            }
            const float bfv = bftile[jj];
            #pragma unroll
            for (int r = 0; r < R; ++r) {
                float f = bfv;
                #pragma unroll
                for (int d = 0; d < DIM; ++d)
                    f = __builtin_fmaf(xr[r][d], yv[d], f);
                accf[r] += __builtin_amdgcn_exp2f(f);   // v_exp_f32
            }
        }
        #pragma unroll
        for (int r = 0; r < R; ++r) accd[r] += (double)accf[r];
    }
    #pragma unroll
    for (int r = 0; r < R; ++r)
        atomicAdd(&acc[i0 + r * BLK], accd[r]);   // fp64 atomic, 16 writers/addr
}

__global__ __launch_bounds__(BLK) void rbf_finish(
    const double* __restrict__ acc, const double* __restrict__ scale,
    float* __restrict__ out, int n)
{
    int i = blockIdx.x * BLK + threadIdx.x;
    if (i < n) out[i] = (float)(acc[i] * scale[i]);
}

extern "C" void kernel_launch(void* const* d_in, const int* in_sizes, int n_in,
                              void* d_out, int out_size, void* d_ws, size_t ws_size,
                              hipStream_t stream)
{
    const float* ls = (const float*)d_in[0];
    const float* x  = (const float*)d_in[1];
    const float* y  = (const float*)d_in[2];
    const int n = in_sizes[1] / DIM;   // 32768
    const int m = in_sizes[2] / DIM;   // 32768
    float* out = (float*)d_out;

    // ws layout: double acc[n] | double scale[n] | float bf[m]  (640 KB total)
    char* ws = (char*)d_ws;
    double* acc   = (double*)ws;
    double* scale = (double*)(ws + (size_t)n * sizeof(double));
    float*  bf    = (float*)(ws + (size_t)n * 2 * sizeof(double));

    const int nm = (n > m) ? n : m;
    rbf_prep<<<(nm + BLK - 1) / BLK, BLK, 0, stream>>>(ls, x, y, n, m, acc, scale, bf);

    const int chunk = m / JSPLIT;
    dim3 grid(n / (BLK * R), JSPLIT);
    rbf_main<<<grid, BLK, 0, stream>>>(ls, x, y, bf, acc, chunk);

    rbf_finish<<<(n + BLK - 1) / BLK, BLK, 0, stream>>>(acc, scale, out, n);
}